// Round 6
// baseline (178.456 us; speedup 1.0000x reference)
//
#include <hip/hip_runtime.h>
#include <math.h>

// DigitCaps dynamic routing, MI355X (gfx950). Round 14: W-in-regs + LDS diet.
// B=256, I=1152 (dim 8), O=10 (dim 16), 3 routing iters.
//
// The launch-bounds map (hard-won over R11-R13):
//   (256,4) budget 128 -> compiler KEEPS the 40-float W frag (R11: VGPR 68)
//   (256,5)/(256,6) budgets 102/85 -> compiler STREAMS W from cache every bb
//     (R12/R13: VGPR 36, 1.47 GB/pass of L2 = 43 us = measured dur; the
//     per-float4 asm pin does NOT stop it -- only 4 floats need be live per
//     asm, so the allocator reloads inside the loop anyway).
// R11's 26% occupancy was caused by its 44 KB LDS (3 blocks/CU), NOT by the
// (256,4) bound: launch_bounds' 2nd arg sets the ALLOCATOR BUDGET, runtime
// residency = min(LDS cap, VGPR cap). With BB=8 (22.5 KB LDS -> 7 blocks fit)
// and VGPR 68 (floor(512/68)=7 waves/SIMD), (256,4) admits 7 blocks/CU =
// 87.5% occupancy cap WITH W in registers. W L2 traffic: 184 MB/pass (~5 us).
//
// Pipeline:
//  K1 k_pass<0>:   partial = sum_i u            (uniform c, no softmax)
//  K2 k_reduce<0>: vsumg = squash(0.1*sum144)   (transposed o-in-8-slot)
//  K3 k_pass<1>:   recompute u, c=softmax(u.vsum), partial = sum_i c*u
//  K4 k_reduce<1>: vsumg += squash(sum144)
//  K5 k_pass<1>:   same (b_ij identity: logits = u.vsum)
//  K6 k_reduce<2>: out = squash(sum144)

constexpr int Bc  = 256;
constexpr int Ic  = 1152;
constexpr int Oc  = 10;
constexpr int DOc = 16;
constexpr int ODc = 160;
constexpr int IT  = 144;   // i-tiles of 8
constexpr int BT  = 32;    // b-tiles of 8
constexpr int BB  = 8;     // b per block

// Sum over the aligned 16-lane group, result in all 16 lanes. Pure VALU (DPP).
__device__ __forceinline__ float dpp16_sum(float v) {
    int s;
    s = __builtin_amdgcn_update_dpp(0, __float_as_int(v), 0xB1, 0xF, 0xF, true);
    v += __int_as_float(s);
    s = __builtin_amdgcn_update_dpp(0, __float_as_int(v), 0x4E, 0xF, 0xF, true);
    v += __int_as_float(s);
    s = __builtin_amdgcn_update_dpp(0, __float_as_int(v), 0x124, 0xF, 0xF, true);
    v += __int_as_float(s);
    s = __builtin_amdgcn_update_dpp(0, __float_as_int(v), 0x128, 0xF, 0xF, true);
    v += __int_as_float(s);
    return v;
}

// ---------------------------------------------------------------- k_pass
// Thread layout: t = il*32 + oh*16 + d.
//   il (0..7): input capsule within the 8-i tile; warp w holds il {2w,2w+1}
//   oh (0..1): o-half; thread owns o = oh*5 .. oh*5+4
//   d  (0..15): out-capsule dim (lane bits 0..3 -> dpp16 reduces over d)
// vsum layout (transposed): vsum[b*256 + d*16 + oh*8 + oq] (slots 5..7
// and 13..15 unused) -> one aligned float4 + one float per thread per bb.
template <int PASS>
__global__ __launch_bounds__(256, 4) void k_pass(const float* __restrict__ x,
                                                 const float* __restrict__ W,
                                                 const float* __restrict__ vsum,
                                                 float* __restrict__ spart) {
    const int bx    = blockIdx.x;
    const int itile = bx % IT;
    const int btile = bx / IT;
    const int t     = threadIdx.x;
    const int d     = t & 15;
    const int oh    = (t >> 4) & 1;
    const int il    = t >> 5;
    const int w     = t >> 6;
    const int i     = itile * 8 + il;
    const int b0    = btile * BB;

    __shared__ __align__(16) float xs[BB * 64];         //  2 KB [bb][il*8+k]
    __shared__ __align__(16) float pacc[4 * BB * ODc];  // 20 KB [w][bb][od]

    // stage x[b0:b0+8][itile*8:+8][8] = 128 float4s
    if (t < 128) {
        int bb = t >> 4;
        int r  = t & 15;
        ((float4*)xs)[t] =
            ((const float4*)(x + (size_t)(b0 + bb) * (Ic * 8) + itile * 64))[r];
    }

    // W fragment for (i, own 5 o's, d): 40 floats in registers.
    // (256,4)'s 128-reg budget is the proven point where the allocator
    // holds this across the bb loop (R11; R12/R13 streamed it at 102/85).
    float4 wr[10];
    {
        const float4* wp =
            (const float4*)(W + (((size_t)i * Oc + oh * 5) * DOc + d) * 8);
#pragma unroll
        for (int oq = 0; oq < 5; ++oq) {
            wr[2 * oq]     = wp[oq * 32];
            wr[2 * oq + 1] = wp[oq * 32 + 1];
        }
    }
    __syncthreads();

#pragma unroll 1
    for (int bb = 0; bb < BB; ++bb) {
        const float4 xa = *((const float4*)(xs + bb * 64 + il * 8));
        const float4 xb = *((const float4*)(xs + bb * 64 + il * 8 + 4));
        float u[5];
#pragma unroll
        for (int oq = 0; oq < 5; ++oq) {
            float4 w0 = wr[2 * oq], w1 = wr[2 * oq + 1];
            u[oq] = w0.x * xa.x + w0.y * xa.y + w0.z * xa.z + w0.w * xa.w +
                    w1.x * xb.x + w1.y * xb.y + w1.z * xb.z + w1.w * xb.w;
        }
        float a5[5];
        if constexpr (PASS == 0) {
#pragma unroll
            for (int oq = 0; oq < 5; ++oq) a5[oq] = u[oq];
        } else {
            const float* vb = vsum + (size_t)(b0 + bb) * 256 + d * 16 + oh * 8;
            const float4 v4 = *((const float4*)vb);
            const float  v1 = vb[4];
            // logits for own 5 o's: DPP reduce over the 16 d-lanes
            float l[5];
            l[0] = dpp16_sum(u[0] * v4.x);
            l[1] = dpp16_sum(u[1] * v4.y);
            l[2] = dpp16_sum(u[2] * v4.z);
            l[3] = dpp16_sum(u[3] * v4.w);
            l[4] = dpp16_sum(u[4] * v1);
            // softmax over 10: cross the oh halves with shfl_xor(16)
            float mo = fmaxf(fmaxf(fmaxf(l[0], l[1]), fmaxf(l[2], l[3])), l[4]);
            float m  = fmaxf(mo, __shfl_xor(mo, 16));
            float se = 0.f;
#pragma unroll
            for (int oq = 0; oq < 5; ++oq) {
                l[oq] = __expf(l[oq] - m);
                se += l[oq];
            }
            se += __shfl_xor(se, 16);
            const float inv = 1.f / se;
#pragma unroll
            for (int oq = 0; oq < 5; ++oq) a5[oq] = (l[oq] * inv) * u[oq];
        }
        // il-pair reduce in-wave; lanes<32 write warp slab (race-free)
#pragma unroll
        for (int oq = 0; oq < 5; ++oq) {
            float a = a5[oq];
            a += __shfl_xor(a, 32);
            if ((t & 63) < 32)
                pacc[(w * BB + bb) * ODc + (oh * 5 + oq) * 16 + d] = a;
        }
    }
    __syncthreads();
    // sum the 4 warp slabs -> per-itile partial (1280 elements)
#pragma unroll
    for (int j = 0; j < 5; ++j) {
        int e = t + j * 256;
        float s = pacc[e] + pacc[1280 + e] + pacc[2560 + e] + pacc[3840 + e];
        spart[(size_t)itile * (Bc * ODc) + b0 * ODc + e] = s;
    }
}

// ---------------------------------------------------------------- k_reduce
// Sum 144 itile-partials -> s[b][160], squash; 4 teams x 36-deep chains.
//  P==0: vsumg = v (s scaled 0.1);  P==1: vsumg += v;  P==2: out = v.
template <int P>
__global__ __launch_bounds__(1024) void k_reduce(const float* __restrict__ part,
                                                 float* __restrict__ vsumg,
                                                 float* __restrict__ out) {
    const int b = blockIdx.x;
    const int t = threadIdx.x;
    __shared__ float red4[4 * ODc];
    const int team = t >> 8, tt = t & 255;
    if (tt < ODc) {
        float s = 0.f;
        const float* pb =
            part + (size_t)team * 36 * (Bc * ODc) + (size_t)b * ODc + tt;
#pragma unroll
        for (int p = 0; p < 36; ++p) s += pb[(size_t)p * (Bc * ODc)];
        red4[team * ODc + tt] = s;
    }
    __syncthreads();
    if (t < ODc) {
        float s = red4[t] + red4[ODc + t] + red4[2 * ODc + t] + red4[3 * ODc + t];
        if (P == 0) s *= 0.1f;
        float sq = dpp16_sum(s * s);
        float v = s * (sq / ((1.f + sq) * sqrtf(sq)));
        if constexpr (P == 2) {
            out[(size_t)b * ODc + t] = v;
        } else {
            const int o = t >> 4, dd = t & 15;
            float* vp = vsumg + (size_t)b * 256 + dd * 16 + (o >= 5 ? 3 + o : o);
            if constexpr (P == 0) *vp = v;
            else                  *vp += v;
        }
    }
}

// ---------------------------------------------------------------- fallback
__global__ void __launch_bounds__(1024, 4)
digitcaps_fallback(const float* __restrict__ x, const float* __restrict__ W,
                   float* __restrict__ out) {
    const int b = blockIdx.x, t = threadIdx.x;
    const int lane = t & 63, wid = t >> 6, d = t & 15, iblk = t >> 4;
    __shared__ __align__(16) float xs[Ic * 8];
    __shared__ __align__(16) float red[16 * ODc];
    __shared__ __align__(16) float svec[ODc], vcur[ODc], vsum[ODc];
    {
        const float4* xg = (const float4*)(x + (size_t)b * (Ic * 8));
        float4* xl = (float4*)xs;
        for (int j = t; j < Ic * 2; j += 1024) xl[j] = xg[j];
    }
    if (t < ODc) vsum[t] = 0.f;
    __syncthreads();
    float acc[Oc], vsr[Oc];
    for (int it = 0; it < 3; ++it) {
#pragma unroll
        for (int o = 0; o < Oc; ++o) { acc[o] = 0.f; vsr[o] = vsum[o * 16 + d]; }
#pragma unroll 1
        for (int chk = 0; chk < 18; ++chk) {
            const int i = chk * 64 + iblk;
            const float4 xa = ((const float4*)(xs + i * 8))[0];
            const float4 xb = ((const float4*)(xs + i * 8))[1];
            const float* wb = W + (((size_t)i * Oc) * DOc + d) * 8;
            float uo[Oc];
#pragma unroll
            for (int o = 0; o < Oc; ++o) {
                const float4* wp = (const float4*)(wb + o * 128);
                float4 w0 = wp[0], w1 = wp[1];
                uo[o] = w0.x * xa.x + w0.y * xa.y + w0.z * xa.z + w0.w * xa.w +
                        w1.x * xb.x + w1.y * xb.y + w1.z * xb.z + w1.w * xb.w;
            }
            float cc[Oc];
            if (it > 0) {
#pragma unroll
                for (int o = 0; o < Oc; ++o) cc[o] = dpp16_sum(uo[o] * vsr[o]);
                float m = cc[0];
#pragma unroll
                for (int o = 1; o < Oc; ++o) m = fmaxf(m, cc[o]);
                float se = 0.f;
#pragma unroll
                for (int o = 0; o < Oc; ++o) { cc[o] = __expf(cc[o] - m); se += cc[o]; }
                float inv = 1.f / se;
#pragma unroll
                for (int o = 0; o < Oc; ++o) acc[o] += cc[o] * inv * uo[o];
            } else {
#pragma unroll
                for (int o = 0; o < Oc; ++o) acc[o] += 0.1f * uo[o];
            }
        }
#pragma unroll
        for (int o = 0; o < Oc; ++o) {
            float a = acc[o];
            a += __shfl_xor(a, 16);
            a += __shfl_xor(a, 32);
            if (lane < 16) red[wid * ODc + o * 16 + lane] = a;
        }
        __syncthreads();
        if (t < ODc) {
            float s = 0.f;
#pragma unroll
            for (int w = 0; w < 16; ++w) s += red[w * ODc + t];
            svec[t] = s;
        }
        __syncthreads();
        if (t < Oc) {
            float sq = 0.f;
#pragma unroll
            for (int dd = 0; dd < DOc; ++dd) sq += svec[t * 16 + dd] * svec[t * 16 + dd];
            float sc = sq / ((1.f + sq) * sqrtf(sq));
#pragma unroll
            for (int dd = 0; dd < DOc; ++dd) {
                float v = svec[t * 16 + dd] * sc;
                vcur[t * 16 + dd] = v;
                vsum[t * 16 + dd] += v;
            }
        }
        __syncthreads();
    }
    if (t < ODc) out[(size_t)b * ODc + t] = vcur[t];
}

// ---------------------------------------------------------------- launcher
extern "C" void kernel_launch(void* const* d_in, const int* in_sizes, int n_in,
                              void* d_out, int out_size, void* d_ws, size_t ws_size,
                              hipStream_t stream) {
    (void)in_sizes; (void)n_in; (void)out_size;
    const float* x = (const float*)d_in[0];   // [256,1152,8]
    const float* W = (const float*)d_in[1];   // [1152,10,16,8]
    float* out     = (float*)d_out;           // [256,10,16]

    const size_t PART_B = (size_t)IT * Bc * ODc * sizeof(float); // 23.59 MB
    const size_t VS_B   = (size_t)Bc * 256 * sizeof(float);      //  0.26 MB

    float* partial = (float*)d_ws;
    float* vsumg   = (float*)((char*)d_ws + PART_B);

    if (ws_size >= PART_B + VS_B) {
        hipLaunchKernelGGL((k_pass<0>), dim3(IT * BT), dim3(256), 0, stream,
                           x, W, nullptr, partial);
        hipLaunchKernelGGL((k_reduce<0>), dim3(Bc), dim3(1024), 0, stream,
                           partial, vsumg, nullptr);
        hipLaunchKernelGGL((k_pass<1>), dim3(IT * BT), dim3(256), 0, stream,
                           x, W, vsumg, partial);
        hipLaunchKernelGGL((k_reduce<1>), dim3(Bc), dim3(1024), 0, stream,
                           partial, vsumg, nullptr);
        hipLaunchKernelGGL((k_pass<1>), dim3(IT * BT), dim3(256), 0, stream,
                           x, W, vsumg, partial);
        hipLaunchKernelGGL((k_reduce<2>), dim3(Bc), dim3(1024), 0, stream,
                           partial, nullptr, out);
    } else {
        hipLaunchKernelGGL(digitcaps_fallback, dim3(Bc), dim3(1024), 0, stream,
                           x, W, out);
    }
}

// Round 7
// 175.788 us; speedup vs baseline: 1.0152x; 1.0152x over previous
//
#include <hip/hip_runtime.h>
#include <math.h>

// DigitCaps dynamic routing, MI355X (gfx950). Round 15: R11 hold + LDS diet.
// B=256, I=1152 (dim 8), O=10 (dim 16), 3 routing iters.
//
// The hold/stream map, corrected (R11-R14 evidence):
//   - BB=16 (trip-16 bb loop), (256,4): compiler HOLDS the 40-float W frag
//     (R11: VGPR 68).
//   - BB=8 (trip-8 loop): compiler STREAMS W from L2 every iteration at ANY
//     launch bounds (R12 (256,6), R13 (256,5)+asm pins, R14 (256,4): all
//     VGPR 36, all ~45 us = 1.47 GB/pass / 34.5 TB/s L2 ceiling).
//   It is the loop trip count / reuse-count heuristic, not the reg budget,
//   and asm pins do not override it.
//
// R15: EXACT R11 loop shape (BB=16, trip-16, (256,4)) but pacc halved to
// [4][8][160] (20 KB) with a uniform mid-loop flush at bb==8: process bb
// 0-7, syncthreads, store half to global, syncthreads, reuse slab for bb
// 8-15. LDS = 4 KB xs + 20 KB pacc = 24 KB -> 6 blocks/CU (VGPR cap 7 at
// 68 regs) = 75% occupancy ceiling (R11 was LDS-capped at 3 blocks/37.5%).
// Held-W L2 traffic: 2304 blocks x 40 KB = 92 MB/pass (~3 us).
//
// Pipeline:
//  K1 k_pass<0>:   partial = sum_i u            (uniform c, no softmax)
//  K2 k_reduce<0>: vsumg = squash(0.1*sum144)   (transposed o-in-8-slot)
//  K3 k_pass<1>:   recompute u, c=softmax(u.vsum), partial = sum_i c*u
//  K4 k_reduce<1>: vsumg += squash(sum144)
//  K5 k_pass<1>:   same (b_ij identity: logits = u.vsum)
//  K6 k_reduce<2>: out = squash(sum144)

constexpr int Bc  = 256;
constexpr int Ic  = 1152;
constexpr int Oc  = 10;
constexpr int DOc = 16;
constexpr int ODc = 160;
constexpr int IT  = 144;   // i-tiles of 8
constexpr int BT  = 16;    // b-tiles of 16
constexpr int BB  = 16;    // b per block (trip-16 loop = the held-W regime)

// Sum over the aligned 16-lane group, result in all 16 lanes. Pure VALU (DPP).
__device__ __forceinline__ float dpp16_sum(float v) {
    int s;
    s = __builtin_amdgcn_update_dpp(0, __float_as_int(v), 0xB1, 0xF, 0xF, true);
    v += __int_as_float(s);
    s = __builtin_amdgcn_update_dpp(0, __float_as_int(v), 0x4E, 0xF, 0xF, true);
    v += __int_as_float(s);
    s = __builtin_amdgcn_update_dpp(0, __float_as_int(v), 0x124, 0xF, 0xF, true);
    v += __int_as_float(s);
    s = __builtin_amdgcn_update_dpp(0, __float_as_int(v), 0x128, 0xF, 0xF, true);
    v += __int_as_float(s);
    return v;
}

// ---------------------------------------------------------------- k_pass
// Thread layout: t = il*32 + oh*16 + d.
//   il (0..7): input capsule within the 8-i tile; warp w holds il {2w,2w+1}
//   oh (0..1): o-half; thread owns o = oh*5 .. oh*5+4
//   d  (0..15): out-capsule dim (lane bits 0..3 -> dpp16 reduces over d)
// vsum layout (transposed): vsum[b*256 + d*16 + oh*8 + oq] (slots 5..7
// and 13..15 unused) -> one aligned float4 + one float per thread per bb.
template <int PASS>
__global__ __launch_bounds__(256, 4) void k_pass(const float* __restrict__ x,
                                                 const float* __restrict__ W,
                                                 const float* __restrict__ vsum,
                                                 float* __restrict__ spart) {
    const int bx    = blockIdx.x;
    const int itile = bx % IT;
    const int btile = bx / IT;
    const int t     = threadIdx.x;
    const int d     = t & 15;
    const int oh    = (t >> 4) & 1;
    const int il    = t >> 5;
    const int w     = t >> 6;
    const int i     = itile * 8 + il;
    const int b0    = btile * BB;

    __shared__ __align__(16) float xs[BB * 64];        //  4 KB [bb][il*8+k]
    __shared__ __align__(16) float pacc[4 * 8 * ODc];  // 20 KB [w][bb&7][od]

    // stage x[b0:b0+16][itile*8:+8][8] = 256 float4s, one per thread
    {
        int bb = t >> 4;
        int r  = t & 15;
        ((float4*)xs)[t] =
            ((const float4*)(x + (size_t)(b0 + bb) * (Ic * 8) + itile * 64))[r];
    }

    // W fragment for (i, own 5 o's, d): 40 floats in registers.
    // Trip-16 bb loop below is the proven configuration where the compiler
    // holds this across the loop (R11); do not shorten the loop.
    float4 wr[10];
    {
        const float4* wp =
            (const float4*)(W + (((size_t)i * Oc + oh * 5) * DOc + d) * 8);
#pragma unroll
        for (int oq = 0; oq < 5; ++oq) {
            wr[2 * oq]     = wp[oq * 32];
            wr[2 * oq + 1] = wp[oq * 32 + 1];
        }
    }
    __syncthreads();

#pragma unroll 1
    for (int bb = 0; bb < BB; ++bb) {
        // mid-loop flush: pacc slab holds 8 bb rows; drain at the boundary.
        if (bb == 8) {
            __syncthreads();
#pragma unroll
            for (int j = 0; j < 5; ++j) {
                int e = t + j * 256;
                float s = pacc[e] + pacc[1280 + e] + pacc[2560 + e] +
                          pacc[3840 + e];
                spart[(size_t)itile * (Bc * ODc) + b0 * ODc + e] = s;
            }
            __syncthreads();
        }
        const float4 xa = *((const float4*)(xs + bb * 64 + il * 8));
        const float4 xb = *((const float4*)(xs + bb * 64 + il * 8 + 4));
        float u[5];
#pragma unroll
        for (int oq = 0; oq < 5; ++oq) {
            float4 w0 = wr[2 * oq], w1 = wr[2 * oq + 1];
            u[oq] = w0.x * xa.x + w0.y * xa.y + w0.z * xa.z + w0.w * xa.w +
                    w1.x * xb.x + w1.y * xb.y + w1.z * xb.z + w1.w * xb.w;
        }
        float a5[5];
        if constexpr (PASS == 0) {
#pragma unroll
            for (int oq = 0; oq < 5; ++oq) a5[oq] = u[oq];
        } else {
            const float* vb = vsum + (size_t)(b0 + bb) * 256 + d * 16 + oh * 8;
            const float4 v4 = *((const float4*)vb);
            const float  v1 = vb[4];
            // logits for own 5 o's: DPP reduce over the 16 d-lanes
            float l[5];
            l[0] = dpp16_sum(u[0] * v4.x);
            l[1] = dpp16_sum(u[1] * v4.y);
            l[2] = dpp16_sum(u[2] * v4.z);
            l[3] = dpp16_sum(u[3] * v4.w);
            l[4] = dpp16_sum(u[4] * v1);
            // softmax over 10: cross the oh halves with shfl_xor(16)
            float mo = fmaxf(fmaxf(fmaxf(l[0], l[1]), fmaxf(l[2], l[3])), l[4]);
            float m  = fmaxf(mo, __shfl_xor(mo, 16));
            float se = 0.f;
#pragma unroll
            for (int oq = 0; oq < 5; ++oq) {
                l[oq] = __expf(l[oq] - m);
                se += l[oq];
            }
            se += __shfl_xor(se, 16);
            const float inv = 1.f / se;
#pragma unroll
            for (int oq = 0; oq < 5; ++oq) a5[oq] = (l[oq] * inv) * u[oq];
        }
        // il-pair reduce in-wave; lanes<32 write warp slab (race-free)
#pragma unroll
        for (int oq = 0; oq < 5; ++oq) {
            float a = a5[oq];
            a += __shfl_xor(a, 32);
            if ((t & 63) < 32)
                pacc[(w * 8 + (bb & 7)) * ODc + (oh * 5 + oq) * 16 + d] = a;
        }
    }
    __syncthreads();
    // drain second half (bb 8..15 -> rows b0+8 .. b0+15)
#pragma unroll
    for (int j = 0; j < 5; ++j) {
        int e = t + j * 256;
        float s = pacc[e] + pacc[1280 + e] + pacc[2560 + e] + pacc[3840 + e];
        spart[(size_t)itile * (Bc * ODc) + (b0 + 8) * ODc + e] = s;
    }
}

// ---------------------------------------------------------------- k_reduce
// Sum 144 itile-partials -> s[b][160], squash; 4 teams x 36-deep chains.
//  P==0: vsumg = v (s scaled 0.1);  P==1: vsumg += v;  P==2: out = v.
template <int P>
__global__ __launch_bounds__(1024) void k_reduce(const float* __restrict__ part,
                                                 float* __restrict__ vsumg,
                                                 float* __restrict__ out) {
    const int b = blockIdx.x;
    const int t = threadIdx.x;
    __shared__ float red4[4 * ODc];
    const int team = t >> 8, tt = t & 255;
    if (tt < ODc) {
        float s = 0.f;
        const float* pb =
            part + (size_t)team * 36 * (Bc * ODc) + (size_t)b * ODc + tt;
#pragma unroll
        for (int p = 0; p < 36; ++p) s += pb[(size_t)p * (Bc * ODc)];
        red4[team * ODc + tt] = s;
    }
    __syncthreads();
    if (t < ODc) {
        float s = red4[t] + red4[ODc + t] + red4[2 * ODc + t] + red4[3 * ODc + t];
        if (P == 0) s *= 0.1f;
        float sq = dpp16_sum(s * s);
        float v = s * (sq / ((1.f + sq) * sqrtf(sq)));
        if constexpr (P == 2) {
            out[(size_t)b * ODc + t] = v;
        } else {
            const int o = t >> 4, dd = t & 15;
            float* vp = vsumg + (size_t)b * 256 + dd * 16 + (o >= 5 ? 3 + o : o);
            if constexpr (P == 0) *vp = v;
            else                  *vp += v;
        }
    }
}

// ---------------------------------------------------------------- fallback
__global__ void __launch_bounds__(1024, 4)
digitcaps_fallback(const float* __restrict__ x, const float* __restrict__ W,
                   float* __restrict__ out) {
    const int b = blockIdx.x, t = threadIdx.x;
    const int lane = t & 63, wid = t >> 6, d = t & 15, iblk = t >> 4;
    __shared__ __align__(16) float xs[Ic * 8];
    __shared__ __align__(16) float red[16 * ODc];
    __shared__ __align__(16) float svec[ODc], vcur[ODc], vsum[ODc];
    {
        const float4* xg = (const float4*)(x + (size_t)b * (Ic * 8));
        float4* xl = (float4*)xs;
        for (int j = t; j < Ic * 2; j += 1024) xl[j] = xg[j];
    }
    if (t < ODc) vsum[t] = 0.f;
    __syncthreads();
    float acc[Oc], vsr[Oc];
    for (int it = 0; it < 3; ++it) {
#pragma unroll
        for (int o = 0; o < Oc; ++o) { acc[o] = 0.f; vsr[o] = vsum[o * 16 + d]; }
#pragma unroll 1
        for (int chk = 0; chk < 18; ++chk) {
            const int i = chk * 64 + iblk;
            const float4 xa = ((const float4*)(xs + i * 8))[0];
            const float4 xb = ((const float4*)(xs + i * 8))[1];
            const float* wb = W + (((size_t)i * Oc) * DOc + d) * 8;
            float uo[Oc];
#pragma unroll
            for (int o = 0; o < Oc; ++o) {
                const float4* wp = (const float4*)(wb + o * 128);
                float4 w0 = wp[0], w1 = wp[1];
                uo[o] = w0.x * xa.x + w0.y * xa.y + w0.z * xa.z + w0.w * xa.w +
                        w1.x * xb.x + w1.y * xb.y + w1.z * xb.z + w1.w * xb.w;
            }
            float cc[Oc];
            if (it > 0) {
#pragma unroll
                for (int o = 0; o < Oc; ++o) cc[o] = dpp16_sum(uo[o] * vsr[o]);
                float m = cc[0];
#pragma unroll
                for (int o = 1; o < Oc; ++o) m = fmaxf(m, cc[o]);
                float se = 0.f;
#pragma unroll
                for (int o = 0; o < Oc; ++o) { cc[o] = __expf(cc[o] - m); se += cc[o]; }
                float inv = 1.f / se;
#pragma unroll
                for (int o = 0; o < Oc; ++o) acc[o] += cc[o] * inv * uo[o];
            } else {
#pragma unroll
                for (int o = 0; o < Oc; ++o) acc[o] += 0.1f * uo[o];
            }
        }
#pragma unroll
        for (int o = 0; o < Oc; ++o) {
            float a = acc[o];
            a += __shfl_xor(a, 16);
            a += __shfl_xor(a, 32);
            if (lane < 16) red[wid * ODc + o * 16 + lane] = a;
        }
        __syncthreads();
        if (t < ODc) {
            float s = 0.f;
#pragma unroll
            for (int w = 0; w < 16; ++w) s += red[w * ODc + t];
            svec[t] = s;
        }
        __syncthreads();
        if (t < Oc) {
            float sq = 0.f;
#pragma unroll
            for (int dd = 0; dd < DOc; ++dd) sq += svec[t * 16 + dd] * svec[t * 16 + dd];
            float sc = sq / ((1.f + sq) * sqrtf(sq));
#pragma unroll
            for (int dd = 0; dd < DOc; ++dd) {
                float v = svec[t * 16 + dd] * sc;
                vcur[t * 16 + dd] = v;
                vsum[t * 16 + dd] += v;
            }
        }
        __syncthreads();
    }
    if (t < ODc) out[(size_t)b * ODc + t] = vcur[t];
}

// ---------------------------------------------------------------- launcher
extern "C" void kernel_launch(void* const* d_in, const int* in_sizes, int n_in,
                              void* d_out, int out_size, void* d_ws, size_t ws_size,
                              hipStream_t stream) {
    (void)in_sizes; (void)n_in; (void)out_size;
    const float* x = (const float*)d_in[0];   // [256,1152,8]
    const float* W = (const float*)d_in[1];   // [1152,10,16,8]
    float* out     = (float*)d_out;           // [256,10,16]

    const size_t PART_B = (size_t)IT * Bc * ODc * sizeof(float); // 23.59 MB
    const size_t VS_B   = (size_t)Bc * 256 * sizeof(float);      //  0.26 MB

    float* partial = (float*)d_ws;
    float* vsumg   = (float*)((char*)d_ws + PART_B);

    if (ws_size >= PART_B + VS_B) {
        hipLaunchKernelGGL((k_pass<0>), dim3(IT * BT), dim3(256), 0, stream,
                           x, W, nullptr, partial);
        hipLaunchKernelGGL((k_reduce<0>), dim3(Bc), dim3(1024), 0, stream,
                           partial, vsumg, nullptr);
        hipLaunchKernelGGL((k_pass<1>), dim3(IT * BT), dim3(256), 0, stream,
                           x, W, vsumg, partial);
        hipLaunchKernelGGL((k_reduce<1>), dim3(Bc), dim3(1024), 0, stream,
                           partial, vsumg, nullptr);
        hipLaunchKernelGGL((k_pass<1>), dim3(IT * BT), dim3(256), 0, stream,
                           x, W, vsumg, partial);
        hipLaunchKernelGGL((k_reduce<2>), dim3(Bc), dim3(1024), 0, stream,
                           partial, nullptr, out);
    } else {
        hipLaunchKernelGGL(digitcaps_fallback, dim3(Bc), dim3(1024), 0, stream,
                           x, W, out);
    }
}